// Round 8
// baseline (323.542 us; speedup 1.0000x reference)
//
#include <hip/hip_runtime.h>
#include <hip/hip_bf16.h>

#define M_DIM 8192
#define N_DIM 4096
#define K_DIM 4096
#define NITER 32   // 32 iters x 2 K-tiles(64) = 4096

typedef __bf16 bf16x8 __attribute__((ext_vector_type(8)));
typedef float f32x16 __attribute__((ext_vector_type(16)));
typedef unsigned short ushort8v __attribute__((ext_vector_type(8)));

typedef const __attribute__((address_space(1))) void gv_t;
typedef __attribute__((address_space(3))) void lv_t;

static __device__ __forceinline__ unsigned short f2bf(float f) {
  unsigned u = __builtin_bit_cast(unsigned, f);
  u += 0x7fffu + ((u >> 16) & 1u);
  return (unsigned short)(u >> 16);
}

// ---------------- pre-pass 1: inverse permutation ----------------
__global__ void k_pinv(const int* __restrict__ ci, int* __restrict__ pinv) {
  int k = blockIdx.x * 256 + threadIdx.x;
  if (k < K_DIM) pinv[ci[k]] = k;
}

// ---------------- pre-pass 2: x fp32 -> bf16 ----------------
__global__ void k_cvt(const float* __restrict__ x, unsigned short* __restrict__ xb) {
  const long n4 = (long)M_DIM * K_DIM / 4;
  for (long i = (long)blockIdx.x * 256 + threadIdx.x; i < n4; i += 2048L * 256) {
    float4 v = *(const float4*)(x + i * 4);
    ushort4 o;
    o.x = f2bf(v.x); o.y = f2bf(v.y); o.z = f2bf(v.z); o.w = f2bf(v.w);
    *(ushort4*)(xb + i * 4) = o;
  }
}

// ---------------- pre-pass 3: dequant + permute + transpose ----------------
__global__ void k_w2t(const int* __restrict__ w, const float* __restrict__ scales,
                      const int* __restrict__ pinv, unsigned short* __restrict__ w2t) {
  __shared__ int tile[64 * 68];
  __shared__ int grp[64];
  __shared__ int krow[64];
  const int n0 = blockIdx.x * 64;
  const int c0 = blockIdx.y * 64;
  const int t = threadIdx.x;
  if (t < 64) {
    int kk = pinv[c0 + t];
    krow[t] = kk;
    grp[t] = kk >> 7;
  }
  __syncthreads();
  {
    const int ci = t >> 2, q = t & 3;
    const int kk = krow[ci];
    const int* src = w + (long)kk * N_DIM + n0 + q * 16;
#pragma unroll
    for (int j = 0; j < 4; ++j) {
      int4 v = *(const int4*)(src + j * 4);
      *(int4*)&tile[ci * 68 + q * 16 + j * 4] = v;
    }
  }
  __syncthreads();
  {
    const int nj = t >> 2, cq = t & 3;
    const int n = n0 + nj;
    unsigned short outv[16];
#pragma unroll
    for (int i = 0; i < 16; ++i) {
      int cii = cq * 16 + i;
      float f = (float)tile[cii * 68 + nj] * scales[grp[cii] * N_DIM + n];
      outv[i] = f2bf(f);
    }
    unsigned short* dst = w2t + (long)n * K_DIM + c0 + cq * 16;
    *(ushort8v*)(dst)     = *(ushort8v*)&outv[0];
    *(ushort8v*)(dst + 8) = *(ushort8v*)&outv[8];
  }
}

// ---------------- main GEMM: 256x256, BK=64, 8 waves, 8-phase, 32x32x16 MFMA ----------------
// buf0 = even K-tile (A @0, B @32768), buf1 = odd (+65536).
// Fragment addr: ((row<<7) | j<<5 | klo) ^ ((row&7)<<4) — the XOR mask lives in bits 4-6,
// so k-sub-block stepping MUST be XOR (r7 bug: '+ (jp<<6)' carried into the row bits / OOB).
// Staging: P0:B1j23 P1:A1j02 P2:A1j13 P3:B0j01 P4:B0j23 P5:A0j02 P6:A0j13 P7:B1j01.
// Gates (FIFO-audited): P3-end vmcnt(2) [last iter vmcnt(0)], P7-end vmcnt(2).
#define RDA(mh, bo, jp) do { \
  af[0][0]=*(const bf16x8*)(lds+(bo)+(vA0^(((2*(jp))    )<<5))+((mh)*2+0)*4096); \
  af[0][1]=*(const bf16x8*)(lds+(bo)+(vA0^(((2*(jp))+1  )<<5))+((mh)*2+0)*4096); \
  af[1][0]=*(const bf16x8*)(lds+(bo)+(vA0^(((2*(jp))    )<<5))+((mh)*2+1)*4096); \
  af[1][1]=*(const bf16x8*)(lds+(bo)+(vA0^(((2*(jp))+1  )<<5))+((mh)*2+1)*4096); } while(0)
#define RDB(bo, jp) do { \
  bf[0][0]=*(const bf16x8*)(lds+(bo)+32768+(vB0^(((2*(jp))  )<<5))      ); \
  bf[0][1]=*(const bf16x8*)(lds+(bo)+32768+(vB0^(((2*(jp))+1)<<5))      ); \
  bf[1][0]=*(const bf16x8*)(lds+(bo)+32768+(vB0^(((2*(jp))  )<<5))+4096 ); \
  bf[1][1]=*(const bf16x8*)(lds+(bo)+32768+(vB0^(((2*(jp))+1)<<5))+4096 ); } while(0)
#define MFMA8(mh) do { \
  acc[(mh)*2+0][0]=__builtin_amdgcn_mfma_f32_32x32x16_bf16(af[0][0],bf[0][0],acc[(mh)*2+0][0],0,0,0); \
  acc[(mh)*2+0][1]=__builtin_amdgcn_mfma_f32_32x32x16_bf16(af[0][0],bf[1][0],acc[(mh)*2+0][1],0,0,0); \
  acc[(mh)*2+1][0]=__builtin_amdgcn_mfma_f32_32x32x16_bf16(af[1][0],bf[0][0],acc[(mh)*2+1][0],0,0,0); \
  acc[(mh)*2+1][1]=__builtin_amdgcn_mfma_f32_32x32x16_bf16(af[1][0],bf[1][0],acc[(mh)*2+1][1],0,0,0); \
  acc[(mh)*2+0][0]=__builtin_amdgcn_mfma_f32_32x32x16_bf16(af[0][1],bf[0][1],acc[(mh)*2+0][0],0,0,0); \
  acc[(mh)*2+0][1]=__builtin_amdgcn_mfma_f32_32x32x16_bf16(af[0][1],bf[1][1],acc[(mh)*2+0][1],0,0,0); \
  acc[(mh)*2+1][0]=__builtin_amdgcn_mfma_f32_32x32x16_bf16(af[1][1],bf[0][1],acc[(mh)*2+1][0],0,0,0); \
  acc[(mh)*2+1][1]=__builtin_amdgcn_mfma_f32_32x32x16_bf16(af[1][1],bf[1][1],acc[(mh)*2+1][1],0,0,0); \
  } while(0)
#define GL(s, d) __builtin_amdgcn_global_load_lds((gv_t*)(s), (lv_t*)(d), 16, 0, 0)
#define BAR_IN() do { __builtin_amdgcn_s_barrier(); \
  asm volatile("s_waitcnt lgkmcnt(0)" ::: "memory"); \
  __builtin_amdgcn_sched_barrier(0); } while(0)
#define BAR_OUT() do { __builtin_amdgcn_sched_barrier(0); \
  __builtin_amdgcn_s_barrier(); __builtin_amdgcn_sched_barrier(0); } while(0)

__global__ __launch_bounds__(512, 2) void k_gemm(const unsigned short* __restrict__ A,
                                                 const unsigned short* __restrict__ Bt,
                                                 const float* __restrict__ bias,
                                                 float* __restrict__ C) {
  __shared__ __attribute__((aligned(16))) char lds[131072];   // 128 KiB

  const int bid = blockIdx.x;                  // 512 blocks, %8==0 -> bijective
  const int swz = (bid & 7) * 64 + (bid >> 3);
  const int by = swz >> 4;                     // 0..31
  const int bx = swz & 15;                     // 0..15

  const int tid = threadIdx.x;
  const int l = tid & 63;
  const int w = tid >> 6;
  const int wr = w >> 2;        // 0..1
  const int wc = w & 3;         // 0..3

  // staging sources (pre-swizzled; LDS dest linear). Rows of 128B; load j = rows [64j,64j+64).
  const int wmask = ((tid >> 3) & 7) << 4;
  const int kbo = ((tid & 7) * 16) ^ wmask;
  const char* srcA = (const char*)A + (size_t)(by * 256 + (tid >> 3)) * (K_DIM * 2) + kbo;
  const char* srcB = (const char*)Bt + (size_t)(bx * 256 + (tid >> 3)) * (K_DIM * 2) + kbo;
  const int stgoff = tid * 16;

  // 32x32 fragment read bases: addr = ((row<<7) | klo) ^ ((row&7)<<4); j-step via ^(j<<5)
  const int lane31 = l & 31;
  const int klo = (l >> 5) << 4;              // 0 or 16 bytes (k-halves within K=16 block)
  const int rA = wr * 128 + lane31;
  const int rB = wc * 64 + lane31;
  const int mk = (l & 7) << 4;                // == ((rA&7)<<4) == ((rB&7)<<4)
  const int vA0 = ((rA << 7) | klo) ^ mk;
  const int vB0 = ((rB << 7) | klo) ^ mk;

  f32x16 acc[4][2];
#pragma unroll
  for (int mi = 0; mi < 4; ++mi)
#pragma unroll
    for (int ni = 0; ni < 2; ++ni)
#pragma unroll
      for (int r = 0; r < 16; ++r) acc[mi][ni][r] = 0.f;

  // ---- prologue: tile0 full (8 loads) + tile1 B j0,j1 ----
#pragma unroll
  for (int j = 0; j < 4; ++j) GL(srcA + j * 524288, lds + j * 8192 + stgoff);
#pragma unroll
  for (int j = 0; j < 4; ++j) GL(srcB + j * 524288, lds + 32768 + j * 8192 + stgoff);
#pragma unroll
  for (int j = 0; j < 2; ++j) GL(srcB + 128 + j * 524288, lds + 98304 + j * 8192 + stgoff);
  asm volatile("s_waitcnt vmcnt(2)" ::: "memory");
  BAR_OUT();

  bf16x8 af[2][2], bf[2][2];

  for (int J = 0; J < NITER; ++J) {
    const bool nl = (J < NITER - 1);
    const long ko1 = (long)(2 * J + 1) * 128;   // odd tile byte-col
    const long ko2 = ko1 + 128;                 // tile 2J+2
    const long ko3 = ko1 + 256;                 // tile 2J+3

    // ===== P0: tile2J kh0(j01) mh0 =====
    RDA(0, 0, 0); RDB(0, 0);
    GL(srcB + ko1 + 2 * 524288, lds + 98304 + 2 * 8192 + stgoff);
    GL(srcB + ko1 + 3 * 524288, lds + 98304 + 3 * 8192 + stgoff);
    BAR_IN();
    __builtin_amdgcn_s_setprio(1); MFMA8(0); __builtin_amdgcn_s_setprio(0);
    BAR_OUT();

    // ===== P1: tile2J kh0 mh1 =====
    RDA(1, 0, 0);
    GL(srcA + ko1 + 0 * 524288, lds + 65536 + 0 * 8192 + stgoff);
    GL(srcA + ko1 + 2 * 524288, lds + 65536 + 2 * 8192 + stgoff);
    BAR_IN();
    __builtin_amdgcn_s_setprio(1); MFMA8(1); __builtin_amdgcn_s_setprio(0);
    BAR_OUT();

    // ===== P2: tile2J kh1(j23) mh0 =====
    RDA(0, 0, 1); RDB(0, 1);
    GL(srcA + ko1 + 1 * 524288, lds + 65536 + 1 * 8192 + stgoff);
    GL(srcA + ko1 + 3 * 524288, lds + 65536 + 3 * 8192 + stgoff);
    BAR_IN();
    __builtin_amdgcn_s_setprio(1); MFMA8(0); __builtin_amdgcn_s_setprio(0);
    BAR_OUT();

    // ===== P3: tile2J kh1 mh1 =====
    RDA(1, 0, 1);
    if (nl) {
      GL(srcB + ko2 + 0 * 524288, lds + 32768 + 0 * 8192 + stgoff);
      GL(srcB + ko2 + 1 * 524288, lds + 32768 + 1 * 8192 + stgoff);
    }
    BAR_IN();
    __builtin_amdgcn_s_setprio(1); MFMA8(1); __builtin_amdgcn_s_setprio(0);
    if (nl) asm volatile("s_waitcnt vmcnt(2)" ::: "memory");   // A1,B1 fully landed
    else    asm volatile("s_waitcnt vmcnt(0)" ::: "memory");
    BAR_OUT();

    // ===== P4: tile2J+1 kh0 mh0 =====
    RDA(0, 65536, 0); RDB(65536, 0);
    if (nl) {
      GL(srcB + ko2 + 2 * 524288, lds + 32768 + 2 * 8192 + stgoff);
      GL(srcB + ko2 + 3 * 524288, lds + 32768 + 3 * 8192 + stgoff);
    }
    BAR_IN();
    __builtin_amdgcn_s_setprio(1); MFMA8(0); __builtin_amdgcn_s_setprio(0);
    BAR_OUT();

    // ===== P5: tile2J+1 kh0 mh1 =====
    RDA(1, 65536, 0);
    if (nl) {
      GL(srcA + ko2 + 0 * 524288, lds + 0 * 8192 + stgoff);
      GL(srcA + ko2 + 2 * 524288, lds + 2 * 8192 + stgoff);
    }
    BAR_IN();
    __builtin_amdgcn_s_setprio(1); MFMA8(1); __builtin_amdgcn_s_setprio(0);
    BAR_OUT();

    // ===== P6: tile2J+1 kh1 mh0 =====
    RDA(0, 65536, 1); RDB(65536, 1);
    if (nl) {
      GL(srcA + ko2 + 1 * 524288, lds + 1 * 8192 + stgoff);
      GL(srcA + ko2 + 3 * 524288, lds + 3 * 8192 + stgoff);
    }
    BAR_IN();
    __builtin_amdgcn_s_setprio(1); MFMA8(0); __builtin_amdgcn_s_setprio(0);
    BAR_OUT();

    // ===== P7: tile2J+1 kh1 mh1 =====
    RDA(1, 65536, 1);
    if (nl) {
      GL(srcB + ko3 + 0 * 524288, lds + 98304 + 0 * 8192 + stgoff);
      GL(srcB + ko3 + 1 * 524288, lds + 98304 + 1 * 8192 + stgoff);
    }
    BAR_IN();
    __builtin_amdgcn_s_setprio(1); MFMA8(1); __builtin_amdgcn_s_setprio(0);
    asm volatile("s_waitcnt vmcnt(2)" ::: "memory");   // A0,B0 fully landed
    BAR_OUT();
  }

  // ---- epilogue: 32x32 C/D layout col=l&31, row=(reg&3)+8*(reg>>2)+4*(l>>5) ----
  const int row0 = by * 256 + wr * 128 + ((l >> 5) << 2);
  const int col0 = bx * 256 + wc * 64 + lane31;
#pragma unroll
  for (int ni = 0; ni < 2; ++ni) {
    const int col = col0 + ni * 32;
    const float bv = bias[col];
#pragma unroll
    for (int mi = 0; mi < 4; ++mi) {
#pragma unroll
      for (int r = 0; r < 16; ++r) {
        const int row = row0 + mi * 32 + (r & 3) + ((r >> 2) << 3);
        C[(size_t)row * N_DIM + col] = acc[mi][ni][r] + bv;
      }
    }
  }
}

// ---------------- fallback ----------------
__global__ void k_fallback(const float* __restrict__ x, const float* __restrict__ scales,
                           const float* __restrict__ bias, const int* __restrict__ w,
                           const int* __restrict__ ci, float* __restrict__ out) {
  const int n = blockIdx.x * 256 + threadIdx.x;
  const int m0 = blockIdx.y * 32;
  float acc[32];
#pragma unroll
  for (int i = 0; i < 32; ++i) acc[i] = 0.f;
  for (int k = 0; k < K_DIM; ++k) {
    int c = ci[k];
    float wv = (float)w[(long)k * N_DIM + n] * scales[(k >> 7) * N_DIM + n];
#pragma unroll 8
    for (int mm = 0; mm < 32; ++mm)
      acc[mm] += x[(long)(m0 + mm) * K_DIM + c] * wv;
  }
  float bv = bias[n];
  for (int mm = 0; mm < 32; ++mm)
    out[(long)(m0 + mm) * N_DIM + n] = acc[mm] + bv;
}

extern "C" void kernel_launch(void* const* d_in, const int* in_sizes, int n_in,
                              void* d_out, int out_size, void* d_ws, size_t ws_size,
                              hipStream_t stream) {
  const float* x      = (const float*)d_in[0];
  const float* scales = (const float*)d_in[1];
  const float* bias   = (const float*)d_in[2];
  const int*   wq     = (const int*)d_in[3];
  const int*   ci     = (const int*)d_in[4];
  float* out = (float*)d_out;

  const size_t xb_bytes  = (size_t)M_DIM * K_DIM * 2;
  const size_t w2t_bytes = (size_t)N_DIM * K_DIM * 2;
  const size_t need = xb_bytes + w2t_bytes + (size_t)K_DIM * 4;

  if (ws_size < need) {
    k_fallback<<<dim3(N_DIM / 256, M_DIM / 32), 256, 0, stream>>>(x, scales, bias, wq, ci, out);
    return;
  }

  unsigned short* xb  = (unsigned short*)d_ws;
  unsigned short* w2t = (unsigned short*)((char*)d_ws + xb_bytes);
  int* pinv           = (int*)((char*)d_ws + xb_bytes + w2t_bytes);

  k_pinv<<<K_DIM / 256, 256, 0, stream>>>(ci, pinv);
  k_cvt<<<2048, 256, 0, stream>>>(x, xb);
  k_w2t<<<dim3(N_DIM / 64, K_DIM / 64), 256, 0, stream>>>(wq, scales, pinv, w2t);
  k_gemm<<<(M_DIM / 256) * (N_DIM / 256), 512, 0, stream>>>(xb, w2t, bias, out);
}

// Round 9
// 323.060 us; speedup vs baseline: 1.0015x; 1.0015x over previous
//
#include <hip/hip_runtime.h>
#include <hip/hip_bf16.h>

#define M_DIM 8192
#define N_DIM 4096
#define K_DIM 4096
#define NITER 32   // 32 iters x 2 K-tiles(64) = 4096

typedef __bf16 bf16x8 __attribute__((ext_vector_type(8)));
typedef float f32x16 __attribute__((ext_vector_type(16)));
typedef unsigned short ushort8v __attribute__((ext_vector_type(8)));

typedef const __attribute__((address_space(1))) void gv_t;
typedef __attribute__((address_space(3))) void lv_t;

static __device__ __forceinline__ unsigned short f2bf(float f) {
  unsigned u = __builtin_bit_cast(unsigned, f);
  u += 0x7fffu + ((u >> 16) & 1u);
  return (unsigned short)(u >> 16);
}

// ---------------- pre-pass 1: inverse permutation ----------------
__global__ void k_pinv(const int* __restrict__ ci, int* __restrict__ pinv) {
  int k = blockIdx.x * 256 + threadIdx.x;
  if (k < K_DIM) pinv[ci[k]] = k;
}

// ---------------- pre-pass 2: x fp32 -> bf16 ----------------
__global__ void k_cvt(const float* __restrict__ x, unsigned short* __restrict__ xb) {
  const long n4 = (long)M_DIM * K_DIM / 4;
  for (long i = (long)blockIdx.x * 256 + threadIdx.x; i < n4; i += 2048L * 256) {
    float4 v = *(const float4*)(x + i * 4);
    ushort4 o;
    o.x = f2bf(v.x); o.y = f2bf(v.y); o.z = f2bf(v.z); o.w = f2bf(v.w);
    *(ushort4*)(xb + i * 4) = o;
  }
}

// ---------------- pre-pass 3: dequant + permute + transpose ----------------
__global__ void k_w2t(const int* __restrict__ w, const float* __restrict__ scales,
                      const int* __restrict__ pinv, unsigned short* __restrict__ w2t) {
  __shared__ int tile[64 * 68];
  __shared__ int grp[64];
  __shared__ int krow[64];
  const int n0 = blockIdx.x * 64;
  const int c0 = blockIdx.y * 64;
  const int t = threadIdx.x;
  if (t < 64) {
    int kk = pinv[c0 + t];
    krow[t] = kk;
    grp[t] = kk >> 7;
  }
  __syncthreads();
  {
    const int ci = t >> 2, q = t & 3;
    const int kk = krow[ci];
    const int* src = w + (long)kk * N_DIM + n0 + q * 16;
#pragma unroll
    for (int j = 0; j < 4; ++j) {
      int4 v = *(const int4*)(src + j * 4);
      *(int4*)&tile[ci * 68 + q * 16 + j * 4] = v;
    }
  }
  __syncthreads();
  {
    const int nj = t >> 2, cq = t & 3;
    const int n = n0 + nj;
    unsigned short outv[16];
#pragma unroll
    for (int i = 0; i < 16; ++i) {
      int cii = cq * 16 + i;
      float f = (float)tile[cii * 68 + nj] * scales[grp[cii] * N_DIM + n];
      outv[i] = f2bf(f);
    }
    unsigned short* dst = w2t + (long)n * K_DIM + c0 + cq * 16;
    *(ushort8v*)(dst)     = *(ushort8v*)&outv[0];
    *(ushort8v*)(dst + 8) = *(ushort8v*)&outv[8];
  }
}

// ---------------- main GEMM: 256x256, BK=64, 8 waves, 8-phase, 32x32x16 MFMA ----------------
// buf0 = even K-tile (A @0, B @32768), buf1 = odd (+65536).
// Swizzle mask m(row) = ((row&7) ^ (((row>>3)&3)<<1)) << 4  (bits 4-6).
//   r8's (row&7)<<4 left stride-8 lane groups colliding 4-way (2.5e7 conflicts);
//   folding row bits 3-4 in makes every contiguous-8 / stride-8 / stride-16 lane
//   group hit 8 distinct 16B slots. k-sub-block step stays XOR (^ j<<5).
// Staging: P0:B1j23 P1:A1j02 P2:A1j13 P3:B0j01 P4:B0j23 P5:A0j02 P6:A0j13 P7:B1j01.
// Gates (FIFO-audited): P3-end vmcnt(2) [last iter vmcnt(0)], P7-end vmcnt(2).
#define RDA(mh, bo, jp) do { \
  af[0][0]=*(const bf16x8*)(lds+(bo)+(vA0^(((2*(jp))    )<<5))+((mh)*2+0)*4096); \
  af[0][1]=*(const bf16x8*)(lds+(bo)+(vA0^(((2*(jp))+1  )<<5))+((mh)*2+0)*4096); \
  af[1][0]=*(const bf16x8*)(lds+(bo)+(vA0^(((2*(jp))    )<<5))+((mh)*2+1)*4096); \
  af[1][1]=*(const bf16x8*)(lds+(bo)+(vA0^(((2*(jp))+1  )<<5))+((mh)*2+1)*4096); } while(0)
#define RDB(bo, jp) do { \
  bf[0][0]=*(const bf16x8*)(lds+(bo)+32768+(vB0^(((2*(jp))  )<<5))      ); \
  bf[0][1]=*(const bf16x8*)(lds+(bo)+32768+(vB0^(((2*(jp))+1)<<5))      ); \
  bf[1][0]=*(const bf16x8*)(lds+(bo)+32768+(vB0^(((2*(jp))  )<<5))+4096 ); \
  bf[1][1]=*(const bf16x8*)(lds+(bo)+32768+(vB0^(((2*(jp))+1)<<5))+4096 ); } while(0)
#define MFMA8(mh) do { \
  acc[(mh)*2+0][0]=__builtin_amdgcn_mfma_f32_32x32x16_bf16(af[0][0],bf[0][0],acc[(mh)*2+0][0],0,0,0); \
  acc[(mh)*2+0][1]=__builtin_amdgcn_mfma_f32_32x32x16_bf16(af[0][0],bf[1][0],acc[(mh)*2+0][1],0,0,0); \
  acc[(mh)*2+1][0]=__builtin_amdgcn_mfma_f32_32x32x16_bf16(af[1][0],bf[0][0],acc[(mh)*2+1][0],0,0,0); \
  acc[(mh)*2+1][1]=__builtin_amdgcn_mfma_f32_32x32x16_bf16(af[1][0],bf[1][0],acc[(mh)*2+1][1],0,0,0); \
  acc[(mh)*2+0][0]=__builtin_amdgcn_mfma_f32_32x32x16_bf16(af[0][1],bf[0][1],acc[(mh)*2+0][0],0,0,0); \
  acc[(mh)*2+0][1]=__builtin_amdgcn_mfma_f32_32x32x16_bf16(af[0][1],bf[1][1],acc[(mh)*2+0][1],0,0,0); \
  acc[(mh)*2+1][0]=__builtin_amdgcn_mfma_f32_32x32x16_bf16(af[1][1],bf[0][1],acc[(mh)*2+1][0],0,0,0); \
  acc[(mh)*2+1][1]=__builtin_amdgcn_mfma_f32_32x32x16_bf16(af[1][1],bf[1][1],acc[(mh)*2+1][1],0,0,0); \
  } while(0)
#define GL(s, d) __builtin_amdgcn_global_load_lds((gv_t*)(s), (lv_t*)(d), 16, 0, 0)
#define BAR_IN() do { __builtin_amdgcn_s_barrier(); \
  asm volatile("s_waitcnt lgkmcnt(0)" ::: "memory"); \
  __builtin_amdgcn_sched_barrier(0); } while(0)
#define BAR_OUT() do { __builtin_amdgcn_sched_barrier(0); \
  __builtin_amdgcn_s_barrier(); __builtin_amdgcn_sched_barrier(0); } while(0)

__global__ __launch_bounds__(512, 2) void k_gemm(const unsigned short* __restrict__ A,
                                                 const unsigned short* __restrict__ Bt,
                                                 const float* __restrict__ bias,
                                                 float* __restrict__ C) {
  __shared__ __attribute__((aligned(16))) char lds[131072];   // 128 KiB

  const int bid = blockIdx.x;                  // 512 blocks, %8==0 -> bijective
  const int swz = (bid & 7) * 64 + (bid >> 3);
  const int by = swz >> 4;                     // 0..31
  const int bx = swz & 15;                     // 0..15

  const int tid = threadIdx.x;
  const int l = tid & 63;
  const int w = tid >> 6;
  const int wr = w >> 2;        // 0..1
  const int wc = w & 3;         // 0..3

  // staging sources (pre-swizzled; LDS dest linear). Rows of 128B; load j = rows [64j,64j+64).
  // row = j*64 + (tid>>3); phys kb = (tid&7)*16; m(row) = ((row&7)^(((row>>3)&3)<<1))<<4
  //   row&7 = (tid>>3)&7; (row>>3)&3 = (tid>>6)&3  (j*64 terms vanish mod 8 / mod 4)
  const int stg_m = ((((tid >> 3) & 7) ^ (((tid >> 6) & 3) << 1)) << 4);
  const int kbo = ((tid & 7) * 16) ^ stg_m;
  const char* srcA = (const char*)A + (size_t)(by * 256 + (tid >> 3)) * (K_DIM * 2) + kbo;
  const char* srcB = (const char*)Bt + (size_t)(bx * 256 + (tid >> 3)) * (K_DIM * 2) + kbo;
  const int stgoff = tid * 16;

  // 32x32 fragment read bases: addr = ((row<<7) | klo) ^ m(row); j-step via ^(j<<5)
  // row = wavebase + (l&31); wavebase ≡ 0 mod 32 -> m depends only on l.
  const int lane31 = l & 31;
  const int klo = (l >> 5) << 4;              // 0 or 16 bytes
  const int rA = wr * 128 + lane31;
  const int rB = wc * 64 + lane31;
  const int mk = (((l & 7) ^ (((l >> 3) & 3) << 1)) << 4);
  const int vA0 = ((rA << 7) | klo) ^ mk;
  const int vB0 = ((rB << 7) | klo) ^ mk;

  f32x16 acc[4][2];
#pragma unroll
  for (int mi = 0; mi < 4; ++mi)
#pragma unroll
    for (int ni = 0; ni < 2; ++ni)
#pragma unroll
      for (int r = 0; r < 16; ++r) acc[mi][ni][r] = 0.f;

  // ---- prologue: tile0 full (8 loads) + tile1 B j0,j1 ----
#pragma unroll
  for (int j = 0; j < 4; ++j) GL(srcA + j * 524288, lds + j * 8192 + stgoff);
#pragma unroll
  for (int j = 0; j < 4; ++j) GL(srcB + j * 524288, lds + 32768 + j * 8192 + stgoff);
#pragma unroll
  for (int j = 0; j < 2; ++j) GL(srcB + 128 + j * 524288, lds + 98304 + j * 8192 + stgoff);
  asm volatile("s_waitcnt vmcnt(2)" ::: "memory");
  BAR_OUT();

  bf16x8 af[2][2], bf[2][2];

  for (int J = 0; J < NITER; ++J) {
    const bool nl = (J < NITER - 1);
    const long ko1 = (long)(2 * J + 1) * 128;   // odd tile byte-col
    const long ko2 = ko1 + 128;                 // tile 2J+2
    const long ko3 = ko1 + 256;                 // tile 2J+3

    // ===== P0: tile2J kh0(j01) mh0 =====
    RDA(0, 0, 0); RDB(0, 0);
    GL(srcB + ko1 + 2 * 524288, lds + 98304 + 2 * 8192 + stgoff);
    GL(srcB + ko1 + 3 * 524288, lds + 98304 + 3 * 8192 + stgoff);
    BAR_IN();
    __builtin_amdgcn_s_setprio(1); MFMA8(0); __builtin_amdgcn_s_setprio(0);
    BAR_OUT();

    // ===== P1: tile2J kh0 mh1 =====
    RDA(1, 0, 0);
    GL(srcA + ko1 + 0 * 524288, lds + 65536 + 0 * 8192 + stgoff);
    GL(srcA + ko1 + 2 * 524288, lds + 65536 + 2 * 8192 + stgoff);
    BAR_IN();
    __builtin_amdgcn_s_setprio(1); MFMA8(1); __builtin_amdgcn_s_setprio(0);
    BAR_OUT();

    // ===== P2: tile2J kh1(j23) mh0 =====
    RDA(0, 0, 1); RDB(0, 1);
    GL(srcA + ko1 + 1 * 524288, lds + 65536 + 1 * 8192 + stgoff);
    GL(srcA + ko1 + 3 * 524288, lds + 65536 + 3 * 8192 + stgoff);
    BAR_IN();
    __builtin_amdgcn_s_setprio(1); MFMA8(0); __builtin_amdgcn_s_setprio(0);
    BAR_OUT();

    // ===== P3: tile2J kh1 mh1 =====
    RDA(1, 0, 1);
    if (nl) {
      GL(srcB + ko2 + 0 * 524288, lds + 32768 + 0 * 8192 + stgoff);
      GL(srcB + ko2 + 1 * 524288, lds + 32768 + 1 * 8192 + stgoff);
    }
    BAR_IN();
    __builtin_amdgcn_s_setprio(1); MFMA8(1); __builtin_amdgcn_s_setprio(0);
    if (nl) asm volatile("s_waitcnt vmcnt(2)" ::: "memory");   // A1,B1 fully landed
    else    asm volatile("s_waitcnt vmcnt(0)" ::: "memory");
    BAR_OUT();

    // ===== P4: tile2J+1 kh0 mh0 =====
    RDA(0, 65536, 0); RDB(65536, 0);
    if (nl) {
      GL(srcB + ko2 + 2 * 524288, lds + 32768 + 2 * 8192 + stgoff);
      GL(srcB + ko2 + 3 * 524288, lds + 32768 + 3 * 8192 + stgoff);
    }
    BAR_IN();
    __builtin_amdgcn_s_setprio(1); MFMA8(0); __builtin_amdgcn_s_setprio(0);
    BAR_OUT();

    // ===== P5: tile2J+1 kh0 mh1 =====
    RDA(1, 65536, 0);
    if (nl) {
      GL(srcA + ko2 + 0 * 524288, lds + 0 * 8192 + stgoff);
      GL(srcA + ko2 + 2 * 524288, lds + 2 * 8192 + stgoff);
    }
    BAR_IN();
    __builtin_amdgcn_s_setprio(1); MFMA8(1); __builtin_amdgcn_s_setprio(0);
    BAR_OUT();

    // ===== P6: tile2J+1 kh1 mh0 =====
    RDA(0, 65536, 1); RDB(65536, 1);
    if (nl) {
      GL(srcA + ko2 + 1 * 524288, lds + 1 * 8192 + stgoff);
      GL(srcA + ko2 + 3 * 524288, lds + 3 * 8192 + stgoff);
    }
    BAR_IN();
    __builtin_amdgcn_s_setprio(1); MFMA8(0); __builtin_amdgcn_s_setprio(0);
    BAR_OUT();

    // ===== P7: tile2J+1 kh1 mh1 =====
    RDA(1, 65536, 1);
    if (nl) {
      GL(srcB + ko3 + 0 * 524288, lds + 98304 + 0 * 8192 + stgoff);
      GL(srcB + ko3 + 1 * 524288, lds + 98304 + 1 * 8192 + stgoff);
    }
    BAR_IN();
    __builtin_amdgcn_s_setprio(1); MFMA8(1); __builtin_amdgcn_s_setprio(0);
    asm volatile("s_waitcnt vmcnt(2)" ::: "memory");   // A0,B0 fully landed
    BAR_OUT();
  }

  // ---- epilogue: 32x32 C/D layout col=l&31, row=(reg&3)+8*(reg>>2)+4*(l>>5) ----
  const int row0 = by * 256 + wr * 128 + ((l >> 5) << 2);
  const int col0 = bx * 256 + wc * 64 + lane31;
#pragma unroll
  for (int ni = 0; ni < 2; ++ni) {
    const int col = col0 + ni * 32;
    const float bv = bias[col];
#pragma unroll
    for (int mi = 0; mi < 4; ++mi) {
#pragma unroll
      for (int r = 0; r < 16; ++r) {
        const int row = row0 + mi * 32 + (r & 3) + ((r >> 2) << 3);
        C[(size_t)row * N_DIM + col] = acc[mi][ni][r] + bv;
      }
    }
  }
}

// ---------------- fallback ----------------
__global__ void k_fallback(const float* __restrict__ x, const float* __restrict__ scales,
                           const float* __restrict__ bias, const int* __restrict__ w,
                           const int* __restrict__ ci, float* __restrict__ out) {
  const int n = blockIdx.x * 256 + threadIdx.x;
  const int m0 = blockIdx.y * 32;
  float acc[32];
#pragma unroll
  for (int i = 0; i < 32; ++i) acc[i] = 0.f;
  for (int k = 0; k < K_DIM; ++k) {
    int c = ci[k];
    float wv = (float)w[(long)k * N_DIM + n] * scales[(k >> 7) * N_DIM + n];
#pragma unroll 8
    for (int mm = 0; mm < 32; ++mm)
      acc[mm] += x[(long)(m0 + mm) * K_DIM + c] * wv;
  }
  float bv = bias[n];
  for (int mm = 0; mm < 32; ++mm)
    out[(long)(m0 + mm) * N_DIM + n] = acc[mm] + bv;
}

extern "C" void kernel_launch(void* const* d_in, const int* in_sizes, int n_in,
                              void* d_out, int out_size, void* d_ws, size_t ws_size,
                              hipStream_t stream) {
  const float* x      = (const float*)d_in[0];
  const float* scales = (const float*)d_in[1];
  const float* bias   = (const float*)d_in[2];
  const int*   wq     = (const int*)d_in[3];
  const int*   ci     = (const int*)d_in[4];
  float* out = (float*)d_out;

  const size_t xb_bytes  = (size_t)M_DIM * K_DIM * 2;
  const size_t w2t_bytes = (size_t)N_DIM * K_DIM * 2;
  const size_t need = xb_bytes + w2t_bytes + (size_t)K_DIM * 4;

  if (ws_size < need) {
    k_fallback<<<dim3(N_DIM / 256, M_DIM / 32), 256, 0, stream>>>(x, scales, bias, wq, ci, out);
    return;
  }

  unsigned short* xb  = (unsigned short*)d_ws;
  unsigned short* w2t = (unsigned short*)((char*)d_ws + xb_bytes);
  int* pinv           = (int*)((char*)d_ws + xb_bytes + w2t_bytes);

  k_pinv<<<K_DIM / 256, 256, 0, stream>>>(ci, pinv);
  k_cvt<<<2048, 256, 0, stream>>>(x, xb);
  k_w2t<<<dim3(N_DIM / 64, K_DIM / 64), 256, 0, stream>>>(wq, scales, pinv, w2t);
  k_gemm<<<(M_DIM / 256) * (N_DIM / 256), 512, 0, stream>>>(xb, w2t, bias, out);
}